// Round 1
// baseline (100.271 us; speedup 1.0000x reference)
//
#include <hip/hip_runtime.h>

typedef _Float16 f16x8 __attribute__((ext_vector_type(8)));
typedef float    f32x4 __attribute__((ext_vector_type(4)));

#define BATCH 65536
#define NIN   128
#define NOUT  128
#define NGRID 8

// ---------------------------------------------------------------------------
// Weight buffer layout in d_ws (fp16), fragment-contiguous for one-ds/global
// 16B load per MFMA B-fragment:
//   flat half index: (kslot*128 + n)*8 + e          kslot = 0..143
//   basis region:  kslot = j   (0..127), e = g      -> coeffs[n][j][g]
//   silu  region:  kslot = 128 + (j>>3), e = j&7    -> base_w[n][j]
// GEMM K-order: basis k = j*8+g (K=1024, ksteps 0..31), silu k = j (K=128,
// ksteps 32..35).  For kstep ks, sub = lane>>4:  kslot = ks*4 + sub.
// ---------------------------------------------------------------------------

__global__ __launch_bounds__(256) void kan_prep(const float* __restrict__ coeffs,
                                                const float* __restrict__ base_w,
                                                _Float16* __restrict__ W) {
    int t = blockIdx.x * 256 + threadIdx.x;   // 0..16383
    int n = t >> 7;        // output index
    int j = t & 127;       // input index
    const float* src = coeffs + (size_t)(n * 128 + j) * 8;
    _Float16*    dst = W + (size_t)(j * 128 + n) * 8;
#pragma unroll
    for (int g = 0; g < 8; ++g) dst[g] = (_Float16)src[g];
    // silu weights
    W[((size_t)(128 + (j >> 3)) * 128 + n) * 8 + (j & 7)] = (_Float16)base_w[n * 128 + j];
}

#define AS 4.2039284307525743f   /* 3.5 * sqrt(log2(e)) ; 1/width = (G-1)/2 = 3.5 */
#define L2E 1.4426950408889634f

__device__ __forceinline__ f16x8 basis8(float xv, const float* bq) {
    f16x8 r;
#pragma unroll
    for (int g = 0; g < 8; ++g) {
        float u = __builtin_fmaf(xv, AS, bq[g]);      // sqrt(log2e)*(x-c_g)/w
        float e = __builtin_amdgcn_exp2f(-(u * u));   // exp(-((x-c)/w)^2)
        r[g] = (_Float16)e;
    }
    return r;
}

__device__ __forceinline__ float silu1(float xv) {
    float p = __builtin_amdgcn_exp2f(-xv * L2E);
    return xv * __builtin_amdgcn_rcpf(1.0f + p);
}

__global__ __launch_bounds__(256) void kan_main(const float* __restrict__ x,
                                                const float* __restrict__ centers,
                                                const _Float16* __restrict__ W,
                                                float* __restrict__ out) {
    const int lane = threadIdx.x & 63;
    const int wave = threadIdx.x >> 6;
    const int l15  = lane & 15;
    const int lhi  = lane >> 4;
    const int row0 = blockIdx.x * 128 + wave * 32;   // wave owns 32 rows x 128 cols

    float bq[8];
#pragma unroll
    for (int g = 0; g < 8; ++g) bq[g] = -centers[g] * AS;

    const float* xrow = x + (size_t)(row0 + l15) * NIN;   // A-frag row for m=0

    f32x4 acc[2][8];
#pragma unroll
    for (int m = 0; m < 2; ++m)
#pragma unroll
        for (int nb = 0; nb < 8; ++nb) acc[m][nb] = (f32x4){0.f, 0.f, 0.f, 0.f};

    // ---- GEMM 1: RBF basis features, K = 1024 (32 ksteps), j = ks*4 + lhi ----
#pragma unroll 2
    for (int ks = 0; ks < 32; ++ks) {
        f16x8 a0 = basis8(xrow[ks * 4 + lhi], bq);
        f16x8 a1 = basis8(xrow[2048 + ks * 4 + lhi], bq);   // m=1: +16 rows
        const _Float16* wp = W + ((size_t)(ks * 4 + lhi) * 128 + l15) * 8;
#pragma unroll
        for (int nb = 0; nb < 8; ++nb) {
            f16x8 b = *(const f16x8*)(wp + (size_t)nb * 16 * 8);
            acc[0][nb] = __builtin_amdgcn_mfma_f32_16x16x32_f16(a0, b, acc[0][nb], 0, 0, 0);
            acc[1][nb] = __builtin_amdgcn_mfma_f32_16x16x32_f16(a1, b, acc[1][nb], 0, 0, 0);
        }
    }

    // ---- GEMM 2: silu base path, K = 128 (4 ksteps), j = ks*32 + lhi*8 + e ----
#pragma unroll
    for (int ks = 0; ks < 4; ++ks) {
        f16x8 a[2];
#pragma unroll
        for (int m = 0; m < 2; ++m) {
            const float* xp = xrow + m * 2048 + ks * 32 + lhi * 8;
            f32x4 v0 = *(const f32x4*)xp;
            f32x4 v1 = *(const f32x4*)(xp + 4);
#pragma unroll
            for (int e = 0; e < 4; ++e) a[m][e]     = (_Float16)silu1(v0[e]);
#pragma unroll
            for (int e = 0; e < 4; ++e) a[m][4 + e] = (_Float16)silu1(v1[e]);
        }
        const _Float16* wp = W + ((size_t)(128 + ks * 4 + lhi) * 128 + l15) * 8;
#pragma unroll
        for (int nb = 0; nb < 8; ++nb) {
            f16x8 b = *(const f16x8*)(wp + (size_t)nb * 16 * 8);
            acc[0][nb] = __builtin_amdgcn_mfma_f32_16x16x32_f16(a[0], b, acc[0][nb], 0, 0, 0);
            acc[1][nb] = __builtin_amdgcn_mfma_f32_16x16x32_f16(a[1], b, acc[1][nb], 0, 0, 0);
        }
    }

    // ---- Epilogue: D[row][col], row = m*16 + lhi*4 + r, col = nb*16 + l15 ----
#pragma unroll
    for (int m = 0; m < 2; ++m)
#pragma unroll
        for (int nb = 0; nb < 8; ++nb)
#pragma unroll
            for (int r = 0; r < 4; ++r)
                out[(size_t)(row0 + m * 16 + lhi * 4 + r) * NOUT + nb * 16 + l15] = acc[m][nb][r];
}

extern "C" void kernel_launch(void* const* d_in, const int* in_sizes, int n_in,
                              void* d_out, int out_size, void* d_ws, size_t ws_size,
                              hipStream_t stream) {
    const float* x       = (const float*)d_in[0];
    const float* coeffs  = (const float*)d_in[1];
    const float* base_w  = (const float*)d_in[2];
    const float* centers = (const float*)d_in[3];
    _Float16* W = (_Float16*)d_ws;   // needs 144*128*8*2 = 294912 bytes

    kan_prep<<<dim3(64), dim3(256), 0, stream>>>(coeffs, base_w, W);
    kan_main<<<dim3(BATCH / 128), dim3(256), 0, stream>>>(x, centers, W, (float*)d_out);
}

// Round 2
// 45.592 us; speedup vs baseline: 2.1993x; 2.1993x over previous
//
#include <hip/hip_runtime.h>

typedef _Float16 f16x8 __attribute__((ext_vector_type(8)));
typedef float    f32x4 __attribute__((ext_vector_type(4)));

#define BATCH 65536
#define NIN   128
#define NOUT  128
#define NKS   36            /* 32 basis k-steps + 4 silu k-steps (K = 1152) */

#define AS  4.2039284307525743f   /* 3.5 * sqrt(log2(e)) ; 1/width = (G-1)/2 = 3.5 */
#define L2E 1.4426950408889634f

// ---------------------------------------------------------------------------
// W2 layout (fp16, produced by kan_prep): for k-step ks (0..35), a 8 KB tile
// of 512 16-byte chunks, chunk index c = nb*64 + l15*4 + lhi, holding
//   kslot = ks*4 + lhi, n = nb*16 + l15, e = 0..7:
//     kslot < 128  -> coeffs[n][j=kslot][g=e]          (basis GEMM, k = j*8+g)
//     kslot >= 128 -> base_w[n][j=(kslot-128)*8 + e]   (silu GEMM, k = j)
// Staging to LDS is then a single linear coalesced region per tile, and the
// per-nb B-fragment ds_read (64 lanes -> 64 consecutive 16B chunks) is
// bank-conflict-free.
// ---------------------------------------------------------------------------

__global__ __launch_bounds__(256) void kan_prep(const float* __restrict__ coeffs,
                                                const float* __restrict__ base_w,
                                                _Float16* __restrict__ W2) {
    int t = blockIdx.x * 256 + threadIdx.x;     // chunk id, 0..18431
    int ks  = t >> 9;
    int c   = t & 511;
    int nb  = c >> 6;
    int l15 = (c >> 2) & 15;
    int lhi = c & 3;
    int n     = nb * 16 + l15;
    int kslot = ks * 4 + lhi;
    f16x8 v;
    if (kslot < 128) {
        const float* src = coeffs + ((size_t)n * 128 + kslot) * 8;
#pragma unroll
        for (int e = 0; e < 8; ++e) v[e] = (_Float16)src[e];
    } else {
        const float* src = base_w + (size_t)n * 128 + (size_t)(kslot - 128) * 8;
#pragma unroll
        for (int e = 0; e < 8; ++e) v[e] = (_Float16)src[e];
    }
    *(f16x8*)((char*)W2 + (size_t)t * 16) = v;
}

__device__ __forceinline__ void gll16(const void* g, void* l) {
    __builtin_amdgcn_global_load_lds(
        (const __attribute__((address_space(1))) unsigned int*)g,
        (__attribute__((address_space(3))) unsigned int*)l, 16, 0, 0);
}

__device__ __forceinline__ f16x8 basis8(float xv, const float* bq) {
    f16x8 r;
#pragma unroll
    for (int g = 0; g < 8; ++g) {
        float u = __builtin_fmaf(xv, AS, bq[g]);      // sqrt(log2e)*(x-c_g)/w
        float e = __builtin_amdgcn_exp2f(-(u * u));   // exp(-((x-c)/w)^2)
        r[g] = (_Float16)e;
    }
    return r;
}

__device__ __forceinline__ float silu1(float xv) {
    float p = __builtin_amdgcn_exp2f(-xv * L2E);
    return xv * __builtin_amdgcn_rcpf(1.0f + p);
}

__global__ __launch_bounds__(256) void kan_main(const float* __restrict__ x,
                                                const float* __restrict__ centers,
                                                const _Float16* __restrict__ W2,
                                                float* __restrict__ out) {
    __shared__ _Float16 smem[2][4096];   // 2 x 8 KB double buffer

    const int tid  = threadIdx.x;
    const int lane = tid & 63;
    const int wave = tid >> 6;
    const int l15  = lane & 15;
    const int lhi  = lane >> 4;
    const int row0 = blockIdx.x * 128 + wave * 32;   // wave owns 32 rows x 128 cols

    float bq[8];
#pragma unroll
    for (int g = 0; g < 8; ++g) bq[g] = -centers[g] * AS;

    const float* xrow = x + (size_t)(row0 + l15) * NIN;   // A row for m=0 fragment

    f32x4 acc[2][8];
#pragma unroll
    for (int m = 0; m < 2; ++m)
#pragma unroll
        for (int nb = 0; nb < 8; ++nb) acc[m][nb] = (f32x4){0.f, 0.f, 0.f, 0.f};

    // stage tile `ks` into buffer `buf`: 512 chunks, 2 per thread, linear
    const char* w2base = (const char*)W2;
#define STAGE(buf, ks)                                                          \
    do {                                                                        \
        const char* _s = w2base + (size_t)(ks) * 8192 + (size_t)tid * 16;       \
        gll16(_s,        (char*)&smem[(buf)][0]    + tid * 16);                 \
        gll16(_s + 4096, (char*)&smem[(buf)][2048] + tid * 16);                 \
    } while (0)

    STAGE(0, 0);
    __syncthreads();

    // ---- basis k-steps 0..31 ----
#pragma unroll 2
    for (int ks = 0; ks < 32; ++ks) {
        const int cur = ks & 1;
        STAGE(cur ^ 1, ks + 1);
        f16x8 a0 = basis8(xrow[ks * 4 + lhi], bq);
        f16x8 a1 = basis8(xrow[2048 + ks * 4 + lhi], bq);   // m=1: +16 rows
        const _Float16* bp = &smem[cur][(size_t)l15 * 32 + lhi * 8];
#pragma unroll
        for (int nb = 0; nb < 8; ++nb) {
            f16x8 b = *(const f16x8*)(bp + nb * 512);
            acc[0][nb] = __builtin_amdgcn_mfma_f32_16x16x32_f16(a0, b, acc[0][nb], 0, 0, 0);
            acc[1][nb] = __builtin_amdgcn_mfma_f32_16x16x32_f16(a1, b, acc[1][nb], 0, 0, 0);
        }
        __syncthreads();
    }

    // ---- silu k-steps 32..35 ----
#pragma unroll 2
    for (int ks = 32; ks < NKS; ++ks) {
        const int cur = ks & 1;
        if (ks + 1 < NKS) STAGE(cur ^ 1, ks + 1);
        f16x8 a[2];
#pragma unroll
        for (int m = 0; m < 2; ++m) {
            const float* xp = xrow + m * 2048 + (ks - 32) * 32 + lhi * 8;
            f32x4 v0 = *(const f32x4*)xp;
            f32x4 v1 = *(const f32x4*)(xp + 4);
#pragma unroll
            for (int e = 0; e < 4; ++e) a[m][e]     = (_Float16)silu1(v0[e]);
#pragma unroll
            for (int e = 0; e < 4; ++e) a[m][4 + e] = (_Float16)silu1(v1[e]);
        }
        const _Float16* bp = &smem[cur][(size_t)l15 * 32 + lhi * 8];
#pragma unroll
        for (int nb = 0; nb < 8; ++nb) {
            f16x8 b = *(const f16x8*)(bp + nb * 512);
            acc[0][nb] = __builtin_amdgcn_mfma_f32_16x16x32_f16(a[0], b, acc[0][nb], 0, 0, 0);
            acc[1][nb] = __builtin_amdgcn_mfma_f32_16x16x32_f16(a[1], b, acc[1][nb], 0, 0, 0);
        }
        __syncthreads();
    }

    // ---- Epilogue: D[row][col], row = m*16 + lhi*4 + r, col = nb*16 + l15 ----
#pragma unroll
    for (int m = 0; m < 2; ++m)
#pragma unroll
        for (int nb = 0; nb < 8; ++nb)
#pragma unroll
            for (int r = 0; r < 4; ++r)
                out[(size_t)(row0 + m * 16 + lhi * 4 + r) * NOUT + nb * 16 + l15] = acc[m][nb][r];
}

extern "C" void kernel_launch(void* const* d_in, const int* in_sizes, int n_in,
                              void* d_out, int out_size, void* d_ws, size_t ws_size,
                              hipStream_t stream) {
    const float* x       = (const float*)d_in[0];
    const float* coeffs  = (const float*)d_in[1];
    const float* base_w  = (const float*)d_in[2];
    const float* centers = (const float*)d_in[3];
    _Float16* W2 = (_Float16*)d_ws;   // 36 * 8192 = 294912 bytes

    kan_prep<<<dim3(72), dim3(256), 0, stream>>>(coeffs, base_w, W2);
    kan_main<<<dim3(BATCH / 128), dim3(256), 0, stream>>>(x, centers, W2, (float*)d_out);
}